// Round 2
// baseline (1057.404 us; speedup 1.0000x reference)
//
#include <hip/hip_runtime.h>
#include <stdint.h>

typedef unsigned short u16;
typedef __attribute__((ext_vector_type(8))) short short8;
typedef __attribute__((ext_vector_type(4))) float f32x4;
typedef __attribute__((ext_vector_type(4))) int i32x4;

#define NB 16
#define NC 512
#define NP 4096
#define NS 77
#define NSK 80
#define NSV 96
#define NCTX 768
#define NH 8
#define NHD 64

__device__ __forceinline__ u16 f2bf(float f) {
  union { float f; uint32_t u; } v; v.f = f;
  uint32_t r = v.u + 0x7fffu + ((v.u >> 16) & 1u);
  return (u16)(r >> 16);
}

// ---------------- K0: cast weights to bf16 ----------------
__global__ void k_convw(const float* __restrict__ qw, const float* __restrict__ ow,
                        u16* __restrict__ qwb, u16* __restrict__ owb) {
  int i = blockIdx.x * 256 + threadIdx.x;  // 262144 total
  qwb[i] = f2bf(qw[i]);
  owb[i] = f2bf(ow[i]);
}

// ---------------- K1: GroupNorm stats -> per-(b,c) scale/shift ----------------
__global__ void k_gnstats(const float* __restrict__ x, const float* __restrict__ gnw,
                          const float* __restrict__ gnb, float* __restrict__ ga,
                          float* __restrict__ gbet) {
  int b = blockIdx.x >> 5, g = blockIdx.x & 31;
  // 16 consecutive channels * 4096 = contiguous 65536 floats
  const float4* base = (const float4*)(x + ((size_t)(b * NC + g * 16)) * NP);
  float s = 0.f, sq = 0.f;
  for (int i = threadIdx.x; i < 16384; i += 256) {
    float4 v = base[i];
    s += v.x + v.y + v.z + v.w;
    sq += v.x * v.x + v.y * v.y + v.z * v.z + v.w * v.w;
  }
  for (int off = 1; off < 64; off <<= 1) { s += __shfl_xor(s, off); sq += __shfl_xor(sq, off); }
  __shared__ float ls[10];
  int w = threadIdx.x >> 6;
  if ((threadIdx.x & 63) == 0) { ls[w] = s; ls[4 + w] = sq; }
  __syncthreads();
  if (threadIdx.x == 0) {
    float S = ls[0] + ls[1] + ls[2] + ls[3];
    float Q = ls[4] + ls[5] + ls[6] + ls[7];
    float mu = S * (1.f / 65536.f);
    float var = Q * (1.f / 65536.f) - mu * mu;
    ls[8] = mu; ls[9] = rsqrtf(var + 1e-5f);
  }
  __syncthreads();
  if (threadIdx.x < 16) {
    int c = g * 16 + threadIdx.x;
    float mu = ls[8], rs = ls[9];
    float A = rs * gnw[c];
    ga[b * NC + c] = A;
    gbet[b * NC + c] = gnb[c] - mu * A;
  }
}

// ---------------- K2: apply GN + transpose -> y (B,P,C) bf16 ----------------
__global__ void k_normT(const float* __restrict__ x, const float* __restrict__ ga,
                        const float* __restrict__ gbet, u16* __restrict__ y) {
  // grid (64 ptile, 8 ctile, 16 b); 64x64 tile transpose through LDS
  int p0 = blockIdx.x * 64, c0 = blockIdx.y * 64, b = blockIdx.z;
  __shared__ float tile[64][65];
  int tid = threadIdx.x;
  int tx = tid & 63, ty = tid >> 6;
  const float* xb = x + ((size_t)(b * NC + c0)) * NP + p0;
#pragma unroll
  for (int rr = 0; rr < 16; rr++) {
    int cl = ty + rr * 4;
    float A = ga[b * NC + c0 + cl], Bt = gbet[b * NC + c0 + cl];
    tile[cl][tx] = xb[(size_t)cl * NP + tx] * A + Bt;
  }
  __syncthreads();
  int pl = tid >> 2, cq = (tid & 3) * 16;
  __align__(16) u16 buf[16];
#pragma unroll
  for (int i = 0; i < 16; i++) buf[i] = f2bf(tile[cq + i][pl]);
  u16* dst = y + ((size_t)(b * NP + p0 + pl)) * NC + c0 + cq;
  *(i32x4*)dst = *(const i32x4*)buf;
  *(i32x4*)(dst + 8) = *(const i32x4*)(buf + 8);
}

// ---------------- K3: LayerNorm + K/V projection ----------------
// K: (B,H,80,64) bf16 (rows 77..79 left as poison -> masked in softmax)
// V: (B,H,64,96) bf16 transposed (cols 77..95 poison -> multiplied by P=0)
__global__ void k_lnkv(const float* __restrict__ ctx, const float* __restrict__ lnw,
                       const float* __restrict__ lnb, const float* __restrict__ kw,
                       const float* __restrict__ kb, const float* __restrict__ vw,
                       const float* __restrict__ vb, u16* __restrict__ K,
                       u16* __restrict__ V) {
  int oc = blockIdx.x, sg = blockIdx.y, b = blockIdx.z;
  __shared__ float cn[16][NCTX];
  int sl = threadIdx.x >> 4, l16 = threadIdx.x & 15;
  int s = sg * 16 + sl;
  if (s < NS) {
    const float* row = ctx + ((size_t)(b * NS + s)) * NCTX;
    float sm = 0.f, sq = 0.f;
    for (int j = l16; j < NCTX; j += 16) { float v = row[j]; sm += v; sq += v * v; }
    for (int off = 1; off < 16; off <<= 1) { sm += __shfl_xor(sm, off); sq += __shfl_xor(sq, off); }
    float mu = sm * (1.f / 768.f);
    float rs = rsqrtf(sq * (1.f / 768.f) - mu * mu + 1e-5f);
    for (int j = l16; j < NCTX; j += 16) cn[sl][j] = (row[j] - mu) * rs * lnw[j] + lnb[j];
  }
  __syncthreads();
  if (s >= NS) return;  // no further barriers below
  int obase = oc * 128 + l16;
  float acc[8] = {0.f, 0.f, 0.f, 0.f, 0.f, 0.f, 0.f, 0.f};
  const float* wr[8];
#pragma unroll
  for (int k = 0; k < 8; k++) {
    int o = obase + k * 16;
    wr[k] = (o < NC) ? kw + (size_t)o * NCTX : vw + (size_t)(o - NC) * NCTX;
  }
  for (int j = 0; j < NCTX; j += 4) {
    float4 c4 = *(const float4*)&cn[sl][j];
#pragma unroll
    for (int k = 0; k < 8; k++) {
      float4 w4 = *(const float4*)(wr[k] + j);
      acc[k] += c4.x * w4.x + c4.y * w4.y + c4.z * w4.z + c4.w * w4.w;
    }
  }
#pragma unroll
  for (int k = 0; k < 8; k++) {
    int o = obase + k * 16;
    if (o < NC) {
      float v = acc[k] + kb[o];
      int h = o >> 6, d = o & 63;
      K[(((size_t)(b * NH) + h) * NSK + s) * NHD + d] = f2bf(v);
    } else {
      int oo = o - NC;
      float v = acc[k] + vb[oo];
      int h = oo >> 6, d = oo & 63;
      V[(((size_t)(b * NH) + h) * NHD + d) * NSV + s] = f2bf(v);
    }
  }
}

// ---------------- K4: Q projection GEMM: Qt[p][o] = sum_c y[p][c]*qw[o][c] + qb ----------------
__global__ __launch_bounds__(256) void k_qproj(const u16* __restrict__ y,
                                               const u16* __restrict__ qwb,
                                               const float* __restrict__ qb,
                                               u16* __restrict__ Qt) {
  int p0 = blockIdx.x * 128, o0 = blockIdx.y * 128, b = blockIdx.z;
  __shared__ u16 As[128 * 32], Bs[128 * 32];
  int t = threadIdx.x, l = t & 63, w = t >> 6;
  int lx = l & 15, ly = l >> 4;
  int wr = w >> 1, wc = w & 1;
  int ar0 = t >> 2, ac0 = (t & 3) * 8;
  int ar1 = (t + 256) >> 2, ac1 = ((t + 256) & 3) * 8;
  const u16* ya = y + ((size_t)(b * NP + p0)) * NC;
  const u16* wa = qwb + (size_t)o0 * NC;
  f32x4 zero = {0.f, 0.f, 0.f, 0.f};
  f32x4 acc[4][4];
#pragma unroll
  for (int mf = 0; mf < 4; mf++)
#pragma unroll
    for (int nf = 0; nf < 4; nf++) acc[mf][nf] = zero;
  i32x4 ra0 = *(const i32x4*)(ya + (size_t)ar0 * NC + ac0);
  i32x4 ra1 = *(const i32x4*)(ya + (size_t)ar1 * NC + ac1);
  i32x4 rb0 = *(const i32x4*)(wa + (size_t)ar0 * NC + ac0);
  i32x4 rb1 = *(const i32x4*)(wa + (size_t)ar1 * NC + ac1);
  for (int kk = 0; kk < 16; kk++) {
    __syncthreads();
    *(i32x4*)&As[ar0 * 32 + ac0] = ra0;
    *(i32x4*)&As[ar1 * 32 + ac1] = ra1;
    *(i32x4*)&Bs[ar0 * 32 + ac0] = rb0;
    *(i32x4*)&Bs[ar1 * 32 + ac1] = rb1;
    __syncthreads();
    if (kk < 15) {
      int ko = (kk + 1) * 32;
      ra0 = *(const i32x4*)(ya + (size_t)ar0 * NC + ko + ac0);
      ra1 = *(const i32x4*)(ya + (size_t)ar1 * NC + ko + ac1);
      rb0 = *(const i32x4*)(wa + (size_t)ar0 * NC + ko + ac0);
      rb1 = *(const i32x4*)(wa + (size_t)ar1 * NC + ko + ac1);
    }
    short8 af[4], bf[4];
#pragma unroll
    for (int mf = 0; mf < 4; mf++) af[mf] = *(const short8*)&As[(wr * 64 + mf * 16 + lx) * 32 + ly * 8];
#pragma unroll
    for (int nf = 0; nf < 4; nf++) bf[nf] = *(const short8*)&Bs[(wc * 64 + nf * 16 + lx) * 32 + ly * 8];
#pragma unroll
    for (int mf = 0; mf < 4; mf++)
#pragma unroll
      for (int nf = 0; nf < 4; nf++)
        acc[mf][nf] = __builtin_amdgcn_mfma_f32_16x16x32_bf16(af[mf], bf[nf], acc[mf][nf], 0, 0, 0);
  }
#pragma unroll
  for (int mf = 0; mf < 4; mf++)
#pragma unroll
    for (int nf = 0; nf < 4; nf++) {
      int o = o0 + wc * 64 + nf * 16 + lx;
      float bias = qb[o];
#pragma unroll
      for (int r = 0; r < 4; r++) {
        int p = p0 + wr * 64 + mf * 16 + ly * 4 + r;
        Qt[((size_t)(b * NP) + p) * NC + o] = f2bf(acc[mf][nf][r] + bias);
      }
    }
}

// ---------------- K5: attention per (b, h, 128-row p tile). AT aliases Qt (safe). ----------------
__global__ __launch_bounds__(256) void k_attn(const u16* __restrict__ Qt, const u16* __restrict__ K,
                                              const u16* __restrict__ V, u16* __restrict__ AT) {
  int pt = blockIdx.x, h = blockIdx.y, b = blockIdx.z;
  int p0 = pt * 128;
  __shared__ u16 smem[25728];          // 51456 B
  u16* Q = smem;                       // stride 72, 128 rows (aliased with P)
  u16* P = smem;                       // stride 104, 128 rows
  u16* Ks = smem + 13312;              // stride 72, 80 rows
  u16* Vs = smem + 19072;              // stride 104, 64 rows
  u16* OS = smem + 13312;              // stride 72, 128 rows (aliases K+V region)
  int t = threadIdx.x, l = t & 63, w = t >> 6;
  int lx = l & 15, ly = l >> 4;
  // stage Q (128x64)
  const u16* qsrc = Qt + ((size_t)(b * NP + p0)) * NC + h * NHD;
#pragma unroll
  for (int i = 0; i < 4; i++) {
    int ch = t + i * 256;
    int row = ch >> 3, c8 = (ch & 7) * 8;
    *(i32x4*)&Q[row * 72 + c8] = *(const i32x4*)(qsrc + (size_t)row * NC + c8);
  }
  // stage K (80x64 contiguous)
  const u16* ksrc = K + ((size_t)(b * NH + h)) * (NSK * NHD);
#pragma unroll
  for (int i = 0; i < 3; i++) {
    int ch = t + i * 256;
    if (ch < 640) {
      int row = ch >> 3, c8 = (ch & 7) * 8;
      *(i32x4*)&Ks[row * 72 + c8] = *(const i32x4*)(ksrc + ch * 8);
    }
  }
  // stage V (64x96 contiguous)
  const u16* vsrc = V + ((size_t)(b * NH + h)) * (NHD * NSV);
#pragma unroll
  for (int i = 0; i < 3; i++) {
    int ch = t + i * 256;
    int row = ch / 12, cc = (ch % 12) * 8;
    *(i32x4*)&Vs[row * 104 + cc] = *(const i32x4*)(vsrc + ch * 8);
  }
  __syncthreads();
  // QK^T: rows p (wave strip of 32), cols s (80)
  f32x4 zero = {0.f, 0.f, 0.f, 0.f};
  f32x4 accS[2][5];
#pragma unroll
  for (int mf = 0; mf < 2; mf++)
#pragma unroll
    for (int nf = 0; nf < 5; nf++) accS[mf][nf] = zero;
  short8 aq[2][2];
#pragma unroll
  for (int mf = 0; mf < 2; mf++)
#pragma unroll
    for (int ks = 0; ks < 2; ks++)
      aq[mf][ks] = *(const short8*)&Q[(w * 32 + mf * 16 + lx) * 72 + ks * 32 + ly * 8];
#pragma unroll
  for (int nf = 0; nf < 5; nf++)
#pragma unroll
    for (int ks = 0; ks < 2; ks++) {
      short8 bk = *(const short8*)&Ks[(nf * 16 + lx) * 72 + ks * 32 + ly * 8];
#pragma unroll
      for (int mf = 0; mf < 2; mf++)
        accS[mf][nf] = __builtin_amdgcn_mfma_f32_16x16x32_bf16(aq[mf][ks], bk, accS[mf][nf], 0, 0, 0);
    }
  __syncthreads();  // all Q reads done before P overwrites the region
  // zero P pad cols 80..95 (this wave's rows)
  {
    int row = w * 32 + (l >> 1), cb = 80 + (l & 1) * 8;
    i32x4 z = {0, 0, 0, 0};
    *(i32x4*)&P[row * 104 + cb] = z;
  }
  // softmax over s; row = w*32+mf*16+ly*4+r, col = nf*16+lx
#pragma unroll
  for (int mf = 0; mf < 2; mf++) {
    float vv[5][4];
    float mx[4] = {-1e30f, -1e30f, -1e30f, -1e30f};
#pragma unroll
    for (int nf = 0; nf < 5; nf++)
#pragma unroll
      for (int r = 0; r < 4; r++) {
        float vx = accS[mf][nf][r] * 0.125f;
        if (nf == 4 && lx >= 13) vx = -1e30f;  // mask s >= 77
        vv[nf][r] = vx;
        mx[r] = fmaxf(mx[r], vx);
      }
#pragma unroll
    for (int off = 1; off < 16; off <<= 1)
#pragma unroll
      for (int r = 0; r < 4; r++) mx[r] = fmaxf(mx[r], __shfl_xor(mx[r], off));
    float sum[4] = {0.f, 0.f, 0.f, 0.f};
#pragma unroll
    for (int nf = 0; nf < 5; nf++)
#pragma unroll
      for (int r = 0; r < 4; r++) {
        float e = __expf(vv[nf][r] - mx[r]);
        vv[nf][r] = e;
        sum[r] += e;
      }
#pragma unroll
    for (int off = 1; off < 16; off <<= 1)
#pragma unroll
      for (int r = 0; r < 4; r++) sum[r] += __shfl_xor(sum[r], off);
#pragma unroll
    for (int r = 0; r < 4; r++) sum[r] = 1.f / sum[r];
#pragma unroll
    for (int nf = 0; nf < 5; nf++)
#pragma unroll
      for (int r = 0; r < 4; r++) {
        int row = w * 32 + mf * 16 + ly * 4 + r;
        P[row * 104 + nf * 16 + lx] = f2bf(vv[nf][r] * sum[r]);
      }
  }
  __syncthreads();
  // PV: out[p][d] = sum_s P[p][s] * V[s][d]
  f32x4 accO[2][4];
#pragma unroll
  for (int mf = 0; mf < 2; mf++)
#pragma unroll
    for (int nf = 0; nf < 4; nf++) accO[mf][nf] = zero;
#pragma unroll
  for (int ks = 0; ks < 3; ks++) {
    short8 ap[2];
#pragma unroll
    for (int mf = 0; mf < 2; mf++)
      ap[mf] = *(const short8*)&P[(w * 32 + mf * 16 + lx) * 104 + ks * 32 + ly * 8];
#pragma unroll
    for (int nf = 0; nf < 4; nf++) {
      short8 bv = *(const short8*)&Vs[(nf * 16 + lx) * 104 + ks * 32 + ly * 8];
#pragma unroll
      for (int mf = 0; mf < 2; mf++)
        accO[mf][nf] = __builtin_amdgcn_mfma_f32_16x16x32_bf16(ap[mf], bv, accO[mf][nf], 0, 0, 0);
    }
  }
  __syncthreads();  // V reads done before OS overwrites region
#pragma unroll
  for (int mf = 0; mf < 2; mf++)
#pragma unroll
    for (int nf = 0; nf < 4; nf++)
#pragma unroll
      for (int r = 0; r < 4; r++) {
        int row = w * 32 + mf * 16 + ly * 4 + r;
        OS[row * 72 + nf * 16 + lx] = f2bf(accO[mf][nf][r]);
      }
  __syncthreads();
  {
    int row = t >> 1, hf = t & 1;
    u16* dst = AT + ((size_t)(b * NP + p0 + row)) * NC + h * NHD + hf * 32;
    const u16* src = &OS[row * 72 + hf * 32];
    *(i32x4*)dst = *(const i32x4*)src;
    *(i32x4*)(dst + 8) = *(const i32x4*)(src + 8);
    *(i32x4*)(dst + 16) = *(const i32x4*)(src + 16);
    *(i32x4*)(dst + 24) = *(const i32x4*)(src + 24);
  }
}

// ---------------- K6: out projection + bias + residual ----------------
// out[b][o][p] = sum_c ow[o][c]*AT[p][c] + ob[o] + x[b][o][p]
__global__ __launch_bounds__(256) void k_outproj(const u16* __restrict__ AT,
                                                 const u16* __restrict__ owb,
                                                 const float* __restrict__ ob,
                                                 const float* __restrict__ x,
                                                 float* __restrict__ out) {
  int p0 = blockIdx.x * 128, o0 = blockIdx.y * 128, b = blockIdx.z;
  __shared__ u16 As[128 * 32], Bs[128 * 32];
  int t = threadIdx.x, l = t & 63, w = t >> 6;
  int lx = l & 15, ly = l >> 4;
  int wr = w >> 1, wc = w & 1;
  int ar0 = t >> 2, ac0 = (t & 3) * 8;
  int ar1 = (t + 256) >> 2, ac1 = ((t + 256) & 3) * 8;
  const u16* wa = owb + (size_t)o0 * NC;          // A operand: weight rows (m = o)
  const u16* ba = AT + ((size_t)(b * NP + p0)) * NC;  // B operand: AT rows (n = p)
  f32x4 zero = {0.f, 0.f, 0.f, 0.f};
  f32x4 acc[4][4];
#pragma unroll
  for (int mf = 0; mf < 4; mf++)
#pragma unroll
    for (int nf = 0; nf < 4; nf++) acc[mf][nf] = zero;
  i32x4 ra0 = *(const i32x4*)(wa + (size_t)ar0 * NC + ac0);
  i32x4 ra1 = *(const i32x4*)(wa + (size_t)ar1 * NC + ac1);
  i32x4 rb0 = *(const i32x4*)(ba + (size_t)ar0 * NC + ac0);
  i32x4 rb1 = *(const i32x4*)(ba + (size_t)ar1 * NC + ac1);
  for (int kk = 0; kk < 16; kk++) {
    __syncthreads();
    *(i32x4*)&As[ar0 * 32 + ac0] = ra0;
    *(i32x4*)&As[ar1 * 32 + ac1] = ra1;
    *(i32x4*)&Bs[ar0 * 32 + ac0] = rb0;
    *(i32x4*)&Bs[ar1 * 32 + ac1] = rb1;
    __syncthreads();
    if (kk < 15) {
      int ko = (kk + 1) * 32;
      ra0 = *(const i32x4*)(wa + (size_t)ar0 * NC + ko + ac0);
      ra1 = *(const i32x4*)(wa + (size_t)ar1 * NC + ko + ac1);
      rb0 = *(const i32x4*)(ba + (size_t)ar0 * NC + ko + ac0);
      rb1 = *(const i32x4*)(ba + (size_t)ar1 * NC + ko + ac1);
    }
    short8 af[4], bf[4];
#pragma unroll
    for (int mf = 0; mf < 4; mf++) af[mf] = *(const short8*)&As[(wr * 64 + mf * 16 + lx) * 32 + ly * 8];
#pragma unroll
    for (int nf = 0; nf < 4; nf++) bf[nf] = *(const short8*)&Bs[(wc * 64 + nf * 16 + lx) * 32 + ly * 8];
#pragma unroll
    for (int mf = 0; mf < 4; mf++)
#pragma unroll
      for (int nf = 0; nf < 4; nf++)
        acc[mf][nf] = __builtin_amdgcn_mfma_f32_16x16x32_bf16(af[mf], bf[nf], acc[mf][nf], 0, 0, 0);
  }
#pragma unroll
  for (int mf = 0; mf < 4; mf++)
#pragma unroll
    for (int r = 0; r < 4; r++) {
      int o = o0 + wr * 64 + mf * 16 + ly * 4 + r;
      float bias = ob[o];
#pragma unroll
      for (int nf = 0; nf < 4; nf++) {
        int p = p0 + wc * 64 + nf * 16 + lx;
        size_t idx = ((size_t)(b * NC) + o) * NP + p;
        out[idx] = acc[mf][nf][r] + bias + x[idx];
      }
    }
}

// ---------------- launch ----------------
extern "C" void kernel_launch(void* const* d_in, const int* in_sizes, int n_in,
                              void* d_out, int out_size, void* d_ws, size_t ws_size,
                              hipStream_t stream) {
  const float* x   = (const float*)d_in[0];
  const float* ctx = (const float*)d_in[1];
  const float* gnw = (const float*)d_in[2];
  const float* gnb = (const float*)d_in[3];
  const float* lnw = (const float*)d_in[4];
  const float* lnb = (const float*)d_in[5];
  const float* qw  = (const float*)d_in[6];
  const float* qb  = (const float*)d_in[7];
  const float* kw  = (const float*)d_in[8];
  const float* kb  = (const float*)d_in[9];
  const float* vw  = (const float*)d_in[10];
  const float* vb  = (const float*)d_in[11];
  const float* ow  = (const float*)d_in[12];
  const float* ob  = (const float*)d_in[13];
  float* out = (float*)d_out;

  char* ws = (char*)d_ws;
  u16* qwb = (u16*)ws;  ws += 524288;
  u16* owb = (u16*)ws;  ws += 524288;
  float* ga = (float*)ws;   ws += 32768;
  float* gbet = (float*)ws; ws += 32768;
  u16* Kb = (u16*)ws;   ws += 1310720;   // 16*8*80*64*2
  u16* Vt = (u16*)ws;   ws += 1572864;   // 16*8*64*96*2
  u16* Qt = (u16*)ws;   ws += 67108864;  // (B,P,C) bf16; also AT (aliased, block-exclusive regions)
  u16* y = (u16*)d_out;                  // xn^T (B,P,C) bf16 in first half of d_out; dead before final writes

  k_convw<<<dim3(1024), dim3(256), 0, stream>>>(qw, ow, qwb, owb);
  k_gnstats<<<dim3(512), dim3(256), 0, stream>>>(x, gnw, gnb, ga, gbet);
  k_normT<<<dim3(64, 8, 16), dim3(256), 0, stream>>>(x, ga, gbet, y);
  k_lnkv<<<dim3(8, 5, 16), dim3(256), 0, stream>>>(ctx, lnw, lnb, kw, kb, vw, vb, Kb, Vt);
  k_qproj<<<dim3(32, 4, 16), dim3(256), 0, stream>>>(y, qwb, qb, Qt);
  k_attn<<<dim3(32, 8, 16), dim3(256), 0, stream>>>(Qt, Kb, Vt, Qt);
  k_outproj<<<dim3(32, 4, 16), dim3(256), 0, stream>>>(Qt, owb, ob, x, out);
}

// Round 3
// 556.003 us; speedup vs baseline: 1.9018x; 1.9018x over previous
//
#include <hip/hip_runtime.h>
#include <stdint.h>

typedef unsigned short u16;
typedef __attribute__((ext_vector_type(8))) short short8;
typedef __attribute__((ext_vector_type(4))) float f32x4;
typedef __attribute__((ext_vector_type(4))) int i32x4;
typedef __attribute__((ext_vector_type(2))) int i32x2;

#define NB 16
#define NC 512
#define NP 4096
#define NS 77
#define NSK 80
#define NSV 96
#define NCTX 768
#define NH 8
#define NHD 64

__device__ __forceinline__ u16 f2bf(float f) {
  union { float f; uint32_t u; } v; v.f = f;
  uint32_t r = v.u + 0x7fffu + ((v.u >> 16) & 1u);
  return (u16)(r >> 16);
}

// ---------------- K0: cast q/out weights to bf16 ----------------
__global__ void k_convw(const float* __restrict__ qw, const float* __restrict__ ow,
                        u16* __restrict__ qwb, u16* __restrict__ owb) {
  int i = blockIdx.x * 256 + threadIdx.x;  // 262144 total
  qwb[i] = f2bf(qw[i]);
  owb[i] = f2bf(ow[i]);
}

// ---------------- K0b: cast k/v weights to concatenated bf16 (1024x768) ----------------
__global__ void k_convw2(const float* __restrict__ kw, const float* __restrict__ vw,
                         u16* __restrict__ kvw) {
  int i = blockIdx.x * 256 + threadIdx.x;  // 393216 total
  kvw[i] = f2bf(kw[i]);
  kvw[393216 + i] = f2bf(vw[i]);
}

// ---------------- K1: GroupNorm stats -> per-(b,c) scale/shift ----------------
__global__ void k_gnstats(const float* __restrict__ x, const float* __restrict__ gnw,
                          const float* __restrict__ gnb, float* __restrict__ ga,
                          float* __restrict__ gbet) {
  int b = blockIdx.x >> 5, g = blockIdx.x & 31;
  const float4* base = (const float4*)(x + ((size_t)(b * NC + g * 16)) * NP);
  float s = 0.f, sq = 0.f;
  for (int i = threadIdx.x; i < 16384; i += 256) {
    float4 v = base[i];
    s += v.x + v.y + v.z + v.w;
    sq += v.x * v.x + v.y * v.y + v.z * v.z + v.w * v.w;
  }
  for (int off = 1; off < 64; off <<= 1) { s += __shfl_xor(s, off); sq += __shfl_xor(sq, off); }
  __shared__ float ls[10];
  int w = threadIdx.x >> 6;
  if ((threadIdx.x & 63) == 0) { ls[w] = s; ls[4 + w] = sq; }
  __syncthreads();
  if (threadIdx.x == 0) {
    float S = ls[0] + ls[1] + ls[2] + ls[3];
    float Q = ls[4] + ls[5] + ls[6] + ls[7];
    float mu = S * (1.f / 65536.f);
    float var = Q * (1.f / 65536.f) - mu * mu;
    ls[8] = mu; ls[9] = rsqrtf(var + 1e-5f);
  }
  __syncthreads();
  if (threadIdx.x < 16) {
    int c = g * 16 + threadIdx.x;
    float mu = ls[8], rs = ls[9];
    float A = rs * gnw[c];
    ga[b * NC + c] = A;
    gbet[b * NC + c] = gnb[c] - mu * A;
  }
}

// ---------------- K2: apply GN + transpose -> y (B,P,C) bf16 ----------------
__global__ void k_normT(const float* __restrict__ x, const float* __restrict__ ga,
                        const float* __restrict__ gbet, u16* __restrict__ y) {
  int p0 = blockIdx.x * 64, c0 = blockIdx.y * 64, b = blockIdx.z;
  __shared__ float tile[64][65];
  int tid = threadIdx.x;
  int tx = tid & 63, ty = tid >> 6;
  const float* xb = x + ((size_t)(b * NC + c0)) * NP + p0;
#pragma unroll
  for (int rr = 0; rr < 16; rr++) {
    int cl = ty + rr * 4;
    float A = ga[b * NC + c0 + cl], Bt = gbet[b * NC + c0 + cl];
    tile[cl][tx] = xb[(size_t)cl * NP + tx] * A + Bt;
  }
  __syncthreads();
  int pl = tid >> 2, cq = (tid & 3) * 16;
  __align__(16) u16 buf[16];
#pragma unroll
  for (int i = 0; i < 16; i++) buf[i] = f2bf(tile[cq + i][pl]);
  u16* dst = y + ((size_t)(b * NP + p0 + pl)) * NC + c0 + cq;
  *(i32x4*)dst = *(const i32x4*)buf;
  *(i32x4*)(dst + 8) = *(const i32x4*)(buf + 8);
}

// ---------------- K3a: LayerNorm context -> cnb (B,80,768) bf16, rows 77..79 zero ----------------
__global__ void k_ln(const float* __restrict__ ctx, const float* __restrict__ lnw,
                     const float* __restrict__ lnb, u16* __restrict__ cnb) {
  int b = blockIdx.y;
  int s = blockIdx.x * 4 + (threadIdx.x >> 6);
  int l = threadIdx.x & 63;
  u16* dst = cnb + ((size_t)(b * NSK + s)) * NCTX;
  if (s >= NS) {
    i32x2 z = {0, 0};
#pragma unroll
    for (int p = 0; p < 3; p++) *(i32x2*)(dst + p * 256 + l * 4) = z;
    return;
  }
  const float* row = ctx + ((size_t)(b * NS + s)) * NCTX;
  float4 v[3];
  float sm = 0.f, sq = 0.f;
#pragma unroll
  for (int p = 0; p < 3; p++) {
    v[p] = *(const float4*)(row + p * 256 + l * 4);
    sm += v[p].x + v[p].y + v[p].z + v[p].w;
    sq += v[p].x * v[p].x + v[p].y * v[p].y + v[p].z * v[p].z + v[p].w * v[p].w;
  }
  for (int off = 1; off < 64; off <<= 1) { sm += __shfl_xor(sm, off); sq += __shfl_xor(sq, off); }
  float mu = sm * (1.f / 768.f);
  float rs = rsqrtf(sq * (1.f / 768.f) - mu * mu + 1e-5f);
#pragma unroll
  for (int p = 0; p < 3; p++) {
    float4 wv = *(const float4*)(lnw + p * 256 + l * 4);
    float4 bv = *(const float4*)(lnb + p * 256 + l * 4);
    float o0 = (v[p].x - mu) * rs * wv.x + bv.x;
    float o1 = (v[p].y - mu) * rs * wv.y + bv.y;
    float o2 = (v[p].z - mu) * rs * wv.z + bv.z;
    float o3 = (v[p].w - mu) * rs * wv.w + bv.w;
    uint32_t lo = (uint32_t)f2bf(o0) | ((uint32_t)f2bf(o1) << 16);
    uint32_t hi = (uint32_t)f2bf(o2) | ((uint32_t)f2bf(o3) << 16);
    i32x2 pk = {(int)lo, (int)hi};
    *(i32x2*)(dst + p * 256 + l * 4) = pk;
  }
}

// ---------------- K3b: K/V projection MFMA GEMM ----------------
// C[o][s] = sum_c kvw[o][c] * cnb[b][s][c];  o in [0,1024), s in [0,80)
// o<512 -> K (B,H,80,64) + kb;  o>=512 -> V (B,H,64,96) transposed + vb
__global__ __launch_bounds__(256) void k_kvproj(const u16* __restrict__ cnb,
                                                const u16* __restrict__ kvw,
                                                const float* __restrict__ kb,
                                                const float* __restrict__ vb,
                                                u16* __restrict__ K, u16* __restrict__ V) {
  int m0 = blockIdx.x * 128, b = blockIdx.y;
  __shared__ u16 As[128 * 32], Bs[80 * 32];
  int t = threadIdx.x, l = t & 63, w = t >> 6;
  int lx = l & 15, ly = l >> 4;
  int ar0 = t >> 2, ac0 = (t & 3) * 8;
  int ar1 = (t + 256) >> 2, ac1 = ((t + 256) & 3) * 8;
  const u16* wa = kvw + (size_t)m0 * NCTX;
  const u16* ca = cnb + ((size_t)(b * NSK)) * NCTX;
  f32x4 zero = {0.f, 0.f, 0.f, 0.f};
  f32x4 acc[2][5];
#pragma unroll
  for (int mf = 0; mf < 2; mf++)
#pragma unroll
    for (int nf = 0; nf < 5; nf++) acc[mf][nf] = zero;
  for (int kk = 0; kk < 24; kk++) {
    int k0 = kk * 32;
    __syncthreads();
    *(i32x4*)&As[ar0 * 32 + ac0] = *(const i32x4*)(wa + (size_t)ar0 * NCTX + k0 + ac0);
    *(i32x4*)&As[ar1 * 32 + ac1] = *(const i32x4*)(wa + (size_t)ar1 * NCTX + k0 + ac1);
    *(i32x4*)&Bs[(t >> 2) * 32 + (t & 3) * 8] =
        *(const i32x4*)(ca + (size_t)(t >> 2) * NCTX + k0 + (t & 3) * 8);
    if (t < 64)
      *(i32x4*)&Bs[(64 + (t >> 2)) * 32 + (t & 3) * 8] =
          *(const i32x4*)(ca + (size_t)(64 + (t >> 2)) * NCTX + k0 + (t & 3) * 8);
    __syncthreads();
    short8 af[2], bf[5];
#pragma unroll
    for (int mf = 0; mf < 2; mf++) af[mf] = *(const short8*)&As[(w * 32 + mf * 16 + lx) * 32 + ly * 8];
#pragma unroll
    for (int nf = 0; nf < 5; nf++) bf[nf] = *(const short8*)&Bs[(nf * 16 + lx) * 32 + ly * 8];
#pragma unroll
    for (int mf = 0; mf < 2; mf++)
#pragma unroll
      for (int nf = 0; nf < 5; nf++)
        acc[mf][nf] = __builtin_amdgcn_mfma_f32_16x16x32_bf16(af[mf], bf[nf], acc[mf][nf], 0, 0, 0);
  }
#pragma unroll
  for (int mf = 0; mf < 2; mf++)
#pragma unroll
    for (int nf = 0; nf < 5; nf++)
#pragma unroll
      for (int r = 0; r < 4; r++) {
        int o = m0 + w * 32 + mf * 16 + ly * 4 + r;
        int s = nf * 16 + lx;
        float val = acc[mf][nf][r];
        if (o < NC) {
          val += kb[o];
          int h = o >> 6, d = o & 63;
          K[(((size_t)(b * NH) + h) * NSK + s) * NHD + d] = f2bf(val);
        } else {
          int oo = o - NC;
          val += vb[oo];
          int h = oo >> 6, d = oo & 63;
          V[(((size_t)(b * NH) + h) * NHD + d) * NSV + s] = f2bf(val);
        }
      }
}

// ---------------- K4: Q projection GEMM: Qt[p][o] = sum_c y[p][c]*qw[o][c] + qb ----------------
__global__ __launch_bounds__(256) void k_qproj(const u16* __restrict__ y,
                                               const u16* __restrict__ qwb,
                                               const float* __restrict__ qb,
                                               u16* __restrict__ Qt) {
  int p0 = blockIdx.x * 128, o0 = blockIdx.y * 128, b = blockIdx.z;
  __shared__ u16 As[128 * 32], Bs[128 * 32];
  int t = threadIdx.x, l = t & 63, w = t >> 6;
  int lx = l & 15, ly = l >> 4;
  int wr = w >> 1, wc = w & 1;
  int ar0 = t >> 2, ac0 = (t & 3) * 8;
  int ar1 = (t + 256) >> 2, ac1 = ((t + 256) & 3) * 8;
  const u16* ya = y + ((size_t)(b * NP + p0)) * NC;
  const u16* wa = qwb + (size_t)o0 * NC;
  f32x4 zero = {0.f, 0.f, 0.f, 0.f};
  f32x4 acc[4][4];
#pragma unroll
  for (int mf = 0; mf < 4; mf++)
#pragma unroll
    for (int nf = 0; nf < 4; nf++) acc[mf][nf] = zero;
  i32x4 ra0 = *(const i32x4*)(ya + (size_t)ar0 * NC + ac0);
  i32x4 ra1 = *(const i32x4*)(ya + (size_t)ar1 * NC + ac1);
  i32x4 rb0 = *(const i32x4*)(wa + (size_t)ar0 * NC + ac0);
  i32x4 rb1 = *(const i32x4*)(wa + (size_t)ar1 * NC + ac1);
  for (int kk = 0; kk < 16; kk++) {
    __syncthreads();
    *(i32x4*)&As[ar0 * 32 + ac0] = ra0;
    *(i32x4*)&As[ar1 * 32 + ac1] = ra1;
    *(i32x4*)&Bs[ar0 * 32 + ac0] = rb0;
    *(i32x4*)&Bs[ar1 * 32 + ac1] = rb1;
    __syncthreads();
    if (kk < 15) {
      int ko = (kk + 1) * 32;
      ra0 = *(const i32x4*)(ya + (size_t)ar0 * NC + ko + ac0);
      ra1 = *(const i32x4*)(ya + (size_t)ar1 * NC + ko + ac1);
      rb0 = *(const i32x4*)(wa + (size_t)ar0 * NC + ko + ac0);
      rb1 = *(const i32x4*)(wa + (size_t)ar1 * NC + ko + ac1);
    }
    short8 af[4], bf[4];
#pragma unroll
    for (int mf = 0; mf < 4; mf++) af[mf] = *(const short8*)&As[(wr * 64 + mf * 16 + lx) * 32 + ly * 8];
#pragma unroll
    for (int nf = 0; nf < 4; nf++) bf[nf] = *(const short8*)&Bs[(wc * 64 + nf * 16 + lx) * 32 + ly * 8];
#pragma unroll
    for (int mf = 0; mf < 4; mf++)
#pragma unroll
      for (int nf = 0; nf < 4; nf++)
        acc[mf][nf] = __builtin_amdgcn_mfma_f32_16x16x32_bf16(af[mf], bf[nf], acc[mf][nf], 0, 0, 0);
  }
#pragma unroll
  for (int mf = 0; mf < 4; mf++)
#pragma unroll
    for (int nf = 0; nf < 4; nf++) {
      int o = o0 + wc * 64 + nf * 16 + lx;
      float bias = qb[o];
#pragma unroll
      for (int r = 0; r < 4; r++) {
        int p = p0 + wr * 64 + mf * 16 + ly * 4 + r;
        Qt[((size_t)(b * NP) + p) * NC + o] = f2bf(acc[mf][nf][r] + bias);
      }
    }
}

// ---------------- K5: attention per (b, h, 128-row p tile). AT aliases Qt (safe). ----------------
__global__ __launch_bounds__(256) void k_attn(const u16* __restrict__ Qt, const u16* __restrict__ K,
                                              const u16* __restrict__ V, u16* __restrict__ AT) {
  int pt = blockIdx.x, h = blockIdx.y, b = blockIdx.z;
  int p0 = pt * 128;
  __shared__ u16 smem[25728];          // 51456 B
  u16* Q = smem;                       // stride 72, 128 rows (aliased with P)
  u16* P = smem;                       // stride 104, 128 rows
  u16* Ks = smem + 13312;              // stride 72, 80 rows
  u16* Vs = smem + 19072;              // stride 104, 64 rows
  u16* OS = smem + 13312;              // stride 72, 128 rows (aliases K+V region)
  int t = threadIdx.x, l = t & 63, w = t >> 6;
  int lx = l & 15, ly = l >> 4;
  const u16* qsrc = Qt + ((size_t)(b * NP + p0)) * NC + h * NHD;
#pragma unroll
  for (int i = 0; i < 4; i++) {
    int ch = t + i * 256;
    int row = ch >> 3, c8 = (ch & 7) * 8;
    *(i32x4*)&Q[row * 72 + c8] = *(const i32x4*)(qsrc + (size_t)row * NC + c8);
  }
  const u16* ksrc = K + ((size_t)(b * NH + h)) * (NSK * NHD);
#pragma unroll
  for (int i = 0; i < 3; i++) {
    int ch = t + i * 256;
    if (ch < 640) {
      int row = ch >> 3, c8 = (ch & 7) * 8;
      *(i32x4*)&Ks[row * 72 + c8] = *(const i32x4*)(ksrc + ch * 8);
    }
  }
  const u16* vsrc = V + ((size_t)(b * NH + h)) * (NHD * NSV);
#pragma unroll
  for (int i = 0; i < 3; i++) {
    int ch = t + i * 256;
    int row = ch / 12, cc = (ch % 12) * 8;
    *(i32x4*)&Vs[row * 104 + cc] = *(const i32x4*)(vsrc + ch * 8);
  }
  __syncthreads();
  f32x4 zero = {0.f, 0.f, 0.f, 0.f};
  f32x4 accS[2][5];
#pragma unroll
  for (int mf = 0; mf < 2; mf++)
#pragma unroll
    for (int nf = 0; nf < 5; nf++) accS[mf][nf] = zero;
  short8 aq[2][2];
#pragma unroll
  for (int mf = 0; mf < 2; mf++)
#pragma unroll
    for (int ks = 0; ks < 2; ks++)
      aq[mf][ks] = *(const short8*)&Q[(w * 32 + mf * 16 + lx) * 72 + ks * 32 + ly * 8];
#pragma unroll
  for (int nf = 0; nf < 5; nf++)
#pragma unroll
    for (int ks = 0; ks < 2; ks++) {
      short8 bk = *(const short8*)&Ks[(nf * 16 + lx) * 72 + ks * 32 + ly * 8];
#pragma unroll
      for (int mf = 0; mf < 2; mf++)
        accS[mf][nf] = __builtin_amdgcn_mfma_f32_16x16x32_bf16(aq[mf][ks], bk, accS[mf][nf], 0, 0, 0);
    }
  __syncthreads();
  {
    int row = w * 32 + (l >> 1), cb = 80 + (l & 1) * 8;
    i32x4 z = {0, 0, 0, 0};
    *(i32x4*)&P[row * 104 + cb] = z;
  }
#pragma unroll
  for (int mf = 0; mf < 2; mf++) {
    float vv[5][4];
    float mx[4] = {-1e30f, -1e30f, -1e30f, -1e30f};
#pragma unroll
    for (int nf = 0; nf < 5; nf++)
#pragma unroll
      for (int r = 0; r < 4; r++) {
        float vx = accS[mf][nf][r] * 0.125f;
        if (nf == 4 && lx >= 13) vx = -1e30f;
        vv[nf][r] = vx;
        mx[r] = fmaxf(mx[r], vx);
      }
#pragma unroll
    for (int off = 1; off < 16; off <<= 1)
#pragma unroll
      for (int r = 0; r < 4; r++) mx[r] = fmaxf(mx[r], __shfl_xor(mx[r], off));
    float sum[4] = {0.f, 0.f, 0.f, 0.f};
#pragma unroll
    for (int nf = 0; nf < 5; nf++)
#pragma unroll
      for (int r = 0; r < 4; r++) {
        float e = __expf(vv[nf][r] - mx[r]);
        vv[nf][r] = e;
        sum[r] += e;
      }
#pragma unroll
    for (int off = 1; off < 16; off <<= 1)
#pragma unroll
      for (int r = 0; r < 4; r++) sum[r] += __shfl_xor(sum[r], off);
#pragma unroll
    for (int r = 0; r < 4; r++) sum[r] = 1.f / sum[r];
#pragma unroll
    for (int nf = 0; nf < 5; nf++)
#pragma unroll
      for (int r = 0; r < 4; r++) {
        int row = w * 32 + mf * 16 + ly * 4 + r;
        P[row * 104 + nf * 16 + lx] = f2bf(vv[nf][r] * sum[r]);
      }
  }
  __syncthreads();
  f32x4 accO[2][4];
#pragma unroll
  for (int mf = 0; mf < 2; mf++)
#pragma unroll
    for (int nf = 0; nf < 4; nf++) accO[mf][nf] = zero;
#pragma unroll
  for (int ks = 0; ks < 3; ks++) {
    short8 ap[2];
#pragma unroll
    for (int mf = 0; mf < 2; mf++)
      ap[mf] = *(const short8*)&P[(w * 32 + mf * 16 + lx) * 104 + ks * 32 + ly * 8];
#pragma unroll
    for (int nf = 0; nf < 4; nf++) {
      short8 bv = *(const short8*)&Vs[(nf * 16 + lx) * 104 + ks * 32 + ly * 8];
#pragma unroll
      for (int mf = 0; mf < 2; mf++)
        accO[mf][nf] = __builtin_amdgcn_mfma_f32_16x16x32_bf16(ap[mf], bv, accO[mf][nf], 0, 0, 0);
    }
  }
  __syncthreads();
#pragma unroll
  for (int mf = 0; mf < 2; mf++)
#pragma unroll
    for (int nf = 0; nf < 4; nf++)
#pragma unroll
      for (int r = 0; r < 4; r++) {
        int row = w * 32 + mf * 16 + ly * 4 + r;
        OS[row * 72 + nf * 16 + lx] = f2bf(accO[mf][nf][r]);
      }
  __syncthreads();
  {
    int row = t >> 1, hf = t & 1;
    u16* dst = AT + ((size_t)(b * NP + p0 + row)) * NC + h * NHD + hf * 32;
    const u16* src = &OS[row * 72 + hf * 32];
    *(i32x4*)dst = *(const i32x4*)src;
    *(i32x4*)(dst + 8) = *(const i32x4*)(src + 8);
    *(i32x4*)(dst + 16) = *(const i32x4*)(src + 16);
    *(i32x4*)(dst + 24) = *(const i32x4*)(src + 24);
  }
}

// ---------------- K6: out projection + bias + residual ----------------
__global__ __launch_bounds__(256) void k_outproj(const u16* __restrict__ AT,
                                                 const u16* __restrict__ owb,
                                                 const float* __restrict__ ob,
                                                 const float* __restrict__ x,
                                                 float* __restrict__ out) {
  int p0 = blockIdx.x * 128, o0 = blockIdx.y * 128, b = blockIdx.z;
  __shared__ u16 As[128 * 32], Bs[128 * 32];
  int t = threadIdx.x, l = t & 63, w = t >> 6;
  int lx = l & 15, ly = l >> 4;
  int wr = w >> 1, wc = w & 1;
  int ar0 = t >> 2, ac0 = (t & 3) * 8;
  int ar1 = (t + 256) >> 2, ac1 = ((t + 256) & 3) * 8;
  const u16* wa = owb + (size_t)o0 * NC;
  const u16* ba = AT + ((size_t)(b * NP + p0)) * NC;
  f32x4 zero = {0.f, 0.f, 0.f, 0.f};
  f32x4 acc[4][4];
#pragma unroll
  for (int mf = 0; mf < 4; mf++)
#pragma unroll
    for (int nf = 0; nf < 4; nf++) acc[mf][nf] = zero;
  i32x4 ra0 = *(const i32x4*)(wa + (size_t)ar0 * NC + ac0);
  i32x4 ra1 = *(const i32x4*)(wa + (size_t)ar1 * NC + ac1);
  i32x4 rb0 = *(const i32x4*)(ba + (size_t)ar0 * NC + ac0);
  i32x4 rb1 = *(const i32x4*)(ba + (size_t)ar1 * NC + ac1);
  for (int kk = 0; kk < 16; kk++) {
    __syncthreads();
    *(i32x4*)&As[ar0 * 32 + ac0] = ra0;
    *(i32x4*)&As[ar1 * 32 + ac1] = ra1;
    *(i32x4*)&Bs[ar0 * 32 + ac0] = rb0;
    *(i32x4*)&Bs[ar1 * 32 + ac1] = rb1;
    __syncthreads();
    if (kk < 15) {
      int ko = (kk + 1) * 32;
      ra0 = *(const i32x4*)(wa + (size_t)ar0 * NC + ko + ac0);
      ra1 = *(const i32x4*)(wa + (size_t)ar1 * NC + ko + ac1);
      rb0 = *(const i32x4*)(ba + (size_t)ar0 * NC + ko + ac0);
      rb1 = *(const i32x4*)(ba + (size_t)ar1 * NC + ko + ac1);
    }
    short8 af[4], bf[4];
#pragma unroll
    for (int mf = 0; mf < 4; mf++) af[mf] = *(const short8*)&As[(wr * 64 + mf * 16 + lx) * 32 + ly * 8];
#pragma unroll
    for (int nf = 0; nf < 4; nf++) bf[nf] = *(const short8*)&Bs[(wc * 64 + nf * 16 + lx) * 32 + ly * 8];
#pragma unroll
    for (int mf = 0; mf < 4; mf++)
#pragma unroll
      for (int nf = 0; nf < 4; nf++)
        acc[mf][nf] = __builtin_amdgcn_mfma_f32_16x16x32_bf16(af[mf], bf[nf], acc[mf][nf], 0, 0, 0);
  }
#pragma unroll
  for (int mf = 0; mf < 4; mf++)
#pragma unroll
    for (int r = 0; r < 4; r++) {
      int o = o0 + wr * 64 + mf * 16 + ly * 4 + r;
      float bias = ob[o];
#pragma unroll
      for (int nf = 0; nf < 4; nf++) {
        int p = p0 + wc * 64 + nf * 16 + lx;
        size_t idx = ((size_t)(b * NC) + o) * NP + p;
        out[idx] = acc[mf][nf][r] + bias + x[idx];
      }
    }
}

// ---------------- launch ----------------
extern "C" void kernel_launch(void* const* d_in, const int* in_sizes, int n_in,
                              void* d_out, int out_size, void* d_ws, size_t ws_size,
                              hipStream_t stream) {
  const float* x   = (const float*)d_in[0];
  const float* ctx = (const float*)d_in[1];
  const float* gnw = (const float*)d_in[2];
  const float* gnb = (const float*)d_in[3];
  const float* lnw = (const float*)d_in[4];
  const float* lnb = (const float*)d_in[5];
  const float* qw  = (const float*)d_in[6];
  const float* qb  = (const float*)d_in[7];
  const float* kw  = (const float*)d_in[8];
  const float* kb  = (const float*)d_in[9];
  const float* vw  = (const float*)d_in[10];
  const float* vb  = (const float*)d_in[11];
  const float* ow  = (const float*)d_in[12];
  const float* ob  = (const float*)d_in[13];
  float* out = (float*)d_out;

  char* ws = (char*)d_ws;
  u16* qwb = (u16*)ws;  ws += 524288;
  u16* owb = (u16*)ws;  ws += 524288;
  float* ga = (float*)ws;   ws += 32768;
  float* gbet = (float*)ws; ws += 32768;
  u16* Kb = (u16*)ws;   ws += 1310720;   // 16*8*80*64*2
  u16* Vt = (u16*)ws;   ws += 1572864;   // 16*8*64*96*2
  u16* Qt = (u16*)ws;   ws += 67108864;  // (B,P,C) bf16; also AT (aliased, block-exclusive regions)

  // d_out upper half hosts cnb + kvw (dead before k_outproj overwrites d_out);
  // d_out lower half hosts y (xn^T, dead before final writes)
  u16* y = (u16*)d_out;
  u16* cnb = (u16*)((char*)d_out + 67108864);            // 16*80*768*2 = 1966080 B
  u16* kvw = (u16*)((char*)d_out + 67108864 + 1966080);  // 1024*768*2 = 1572864 B

  k_convw<<<dim3(1024), dim3(256), 0, stream>>>(qw, ow, qwb, owb);
  k_convw2<<<dim3(1536), dim3(256), 0, stream>>>(kw, vw, kvw);
  k_gnstats<<<dim3(512), dim3(256), 0, stream>>>(x, gnw, gnb, ga, gbet);
  k_normT<<<dim3(64, 8, 16), dim3(256), 0, stream>>>(x, ga, gbet, y);
  k_ln<<<dim3(20, 16), dim3(256), 0, stream>>>(ctx, lnw, lnb, cnb);
  k_kvproj<<<dim3(8, 16), dim3(256), 0, stream>>>(cnb, kvw, kb, vb, Kb, Vt);
  k_qproj<<<dim3(32, 4, 16), dim3(256), 0, stream>>>(y, qwb, qb, Qt);
  k_attn<<<dim3(32, 8, 16), dim3(256), 0, stream>>>(Qt, Kb, Vt, Qt);
  k_outproj<<<dim3(32, 4, 16), dim3(256), 0, stream>>>(Qt, owb, ob, x, out);
}